// Round 2
// baseline (648.135 us; speedup 1.0000x reference)
//
#include <hip/hip_runtime.h>
#include <hip/hip_bf16.h>
#include <stdint.h>

typedef unsigned short u16;
typedef __attribute__((ext_vector_type(8))) short short8;
typedef __attribute__((ext_vector_type(4))) float float4v;

#define NNODES 11201
#define MPAD   11264
#define EEDGES 100000
#define RREL   5
#define DDIM   512
#define XLW    2560      // RREL*DDIM
#define FRAMES 1200
#define OUTC   1712      // FRAMES + DDIM

__device__ __forceinline__ float bf2f(u16 h) {
    return __uint_as_float(((uint32_t)h) << 16);
}
__device__ __forceinline__ u16 f2bf(float f) {
    uint32_t x = __float_as_uint(f);
    x += 0x7fffu + ((x >> 16) & 1u);   // RNE
    return (u16)(x >> 16);
}

// ---------------- CSR build ----------------
__global__ void hist_k(const int* __restrict__ rows, int* __restrict__ counts) {
    int tid = blockIdx.x * 256 + threadIdx.x;
    if (tid >= RREL * EEDGES) return;
    int r = tid / EEDGES;
    atomicAdd(&counts[r * NNODES + rows[tid]], 1);
}

__global__ __launch_bounds__(1024) void scan_offsets(const int* __restrict__ counts,
                                                     int* __restrict__ offs) {
    const int N = NNODES;
    int r = blockIdx.x;
    const int* c = counts + (size_t)r * N;
    int* o = offs + (size_t)r * (N + 1);
    __shared__ int sm[1024];
    int carry = 0;
    for (int base = 0; base < N; base += 1024) {
        int idx = base + threadIdx.x;
        int v = (idx < N) ? c[idx] : 0;
        sm[threadIdx.x] = v;
        __syncthreads();
        int accv = v;
        for (int off = 1; off < 1024; off <<= 1) {
            int t = (threadIdx.x >= off) ? sm[threadIdx.x - off] : 0;
            __syncthreads();
            accv += t;
            sm[threadIdx.x] = accv;
            __syncthreads();
        }
        if (idx < N) o[idx] = carry + accv - v;   // exclusive
        carry += sm[1023];
        __syncthreads();
    }
    if (threadIdx.x == 0) o[N] = carry;
}

__global__ void cursor_init(const int* __restrict__ offs, int* __restrict__ cursor) {
    int i = blockIdx.x * 256 + threadIdx.x;
    if (i >= RREL * NNODES) return;
    int r = i / NNODES, n = i - r * NNODES;
    cursor[i] = offs[r * (NNODES + 1) + n];
}

__global__ void scatter_k(const int* __restrict__ rows, const int* __restrict__ cols,
                          const float* __restrict__ vals, int* __restrict__ cursor,
                          int* __restrict__ colS, float* __restrict__ valS) {
    int tid = blockIdx.x * 256 + threadIdx.x;
    if (tid >= RREL * EEDGES) return;
    int r = tid / EEDGES;
    int row = rows[tid];
    int pos = atomicAdd(&cursor[r * NNODES + row], 1);
    colS[(size_t)r * EEDGES + pos] = cols[tid];
    valS[(size_t)r * EEDGES + pos] = vals[tid];
}

// ---------------- input assembly (fp32 -> bf16) ----------------
__global__ void build_x(const float* __restrict__ frame_emb, const float* __restrict__ role_emb,
                        const int* __restrict__ fe_ids, u16* __restrict__ x) {
    int t = blockIdx.x * 256 + threadIdx.x;       // NNODES*128 threads, 4 elems each
    int row = t >> 7, c4 = (t & 127) << 2;
    if (row >= NNODES) return;
    const float* src = (row < FRAMES) ? (frame_emb + (size_t)row * DDIM)
                                      : (role_emb + (size_t)fe_ids[row - FRAMES] * DDIM);
    float4 v = *(const float4*)(src + c4);
    ushort4 o = { f2bf(v.x), f2bf(v.y), f2bf(v.z), f2bf(v.w) };
    *(ushort4*)(x + (size_t)row * DDIM + c4) = o;
}

__global__ void build_tsp(const float* __restrict__ ts, u16* __restrict__ tsp) {
    int t = blockIdx.x * 256 + threadIdx.x;       // 128*2048/4 = 65536 threads
    int row = t >> 9, c4 = (t & 511) << 2;
    ushort4 o = {0, 0, 0, 0};
    if (row < 32) {
        float4 v = *(const float4*)(ts + (size_t)row * 2048 + c4);
        o = ushort4{ f2bf(v.x), f2bf(v.y), f2bf(v.z), f2bf(v.w) };
    }
    *(ushort4*)(tsp + (size_t)row * 2048 + c4) = o;
}

// ---------------- fp32 -> bf16 transpose (batched over z) ----------------
__global__ void transpose_f2b(const float* __restrict__ in, u16* __restrict__ out,
                              int rows, int cols) {
    __shared__ u16 tile[32][33];
    in  += (size_t)blockIdx.z * rows * cols;
    out += (size_t)blockIdx.z * rows * cols;
    int c0 = blockIdx.x * 32, r0 = blockIdx.y * 32;
    int tx = threadIdx.x & 31, ty = threadIdx.x >> 5;   // 256 threads
    #pragma unroll
    for (int i = 0; i < 4; ++i) {
        int rr = ty + i * 8;
        tile[rr][tx] = f2bf(in[(size_t)(r0 + rr) * cols + c0 + tx]);
    }
    __syncthreads();
    #pragma unroll
    for (int i = 0; i < 4; ++i) {
        int rr = ty + i * 8;
        out[(size_t)(c0 + rr) * rows + r0 + tx] = tile[tx][rr];
    }
}

// ---------------- BT-GEMM: C[m][n] = sum_k A[m][k]*Bt[n][k], m97 structure ----------------
// EPI: 0=store, 1=bias+relu, 2=bias, 3=bias+tanh.  FOUT: store fp32 instead of bf16.
template<int EPI, bool FOUT>
__global__ __launch_bounds__(256)
void gemm_bt(const u16* __restrict__ A, const u16* __restrict__ Bt,
             void* __restrict__ Cv, const float* __restrict__ bias,
             int K, int lda, int ldb, int ldc, int mGuard, int nGuard)
{
    __shared__ u16 As[128 * 32];
    __shared__ u16 Bs[128 * 32];
    const int tid = threadIdx.x;
    const int wave = tid >> 6, lane = tid & 63;
    const int m0 = blockIdx.y * 128, n0 = blockIdx.x * 128;
    const int srow = lane >> 2;            // 16 rows per 1KB wave-stage
    const int skoff = (lane & 3) << 3;     // 4 chunks of 8 bf16
    const int fr = lane & 15, quad = lane >> 4;
    const int wm = (wave & 1) << 6, wn = (wave >> 1) << 6;
    float4v acc[4][4] = {};

    for (int k0 = 0; k0 < K; k0 += 32) {
        #pragma unroll
        for (int i = 0; i < 2; ++i) {
            const int rb = (wave + i * 4) << 4;   // 0,16,...,112
            const u16* ga = A  + (size_t)(m0 + rb + srow) * lda + (k0 + skoff);
            const u16* gb = Bt + (size_t)(n0 + rb + srow) * ldb + (k0 + skoff);
            __builtin_amdgcn_global_load_lds(
                (const __attribute__((address_space(1))) unsigned int*)ga,
                (__attribute__((address_space(3))) unsigned int*)(As + rb * 32), 16, 0, 0);
            __builtin_amdgcn_global_load_lds(
                (const __attribute__((address_space(1))) unsigned int*)gb,
                (__attribute__((address_space(3))) unsigned int*)(Bs + rb * 32), 16, 0, 0);
        }
        __syncthreads();
        short8 a[4], b[4];
        #pragma unroll
        for (int t = 0; t < 4; ++t)
            a[t] = *(const short8*)(As + ((wm + t * 16 + fr) << 5) + (quad << 3));
        #pragma unroll
        for (int t = 0; t < 4; ++t)
            b[t] = *(const short8*)(Bs + ((wn + t * 16 + fr) << 5) + (quad << 3));
        #pragma unroll
        for (int i = 0; i < 4; ++i)
            #pragma unroll
            for (int j = 0; j < 4; ++j)
                acc[i][j] = __builtin_amdgcn_mfma_f32_16x16x32_bf16(a[i], b[j], acc[i][j], 0, 0, 0);
        __syncthreads();
    }

    #pragma unroll
    for (int i = 0; i < 4; ++i) {
        #pragma unroll
        for (int j = 0; j < 4; ++j) {
            const int n = n0 + wn + j * 16 + fr;
            float bv = 0.f;
            if (EPI != 0) { if (n < nGuard) bv = bias[n]; }
            #pragma unroll
            for (int rg = 0; rg < 4; ++rg) {
                const int m = m0 + wm + i * 16 + (quad << 2) + rg;
                if (m < mGuard && n < nGuard) {
                    float v = acc[i][j][rg];
                    if (EPI != 0) v += bv;
                    if (EPI == 1) v = fmaxf(v, 0.f);
                    if (EPI == 3) v = tanhf(v);
                    if (FOUT) ((float*)Cv)[(size_t)m * ldc + n] = v;
                    else      ((u16*)Cv)[(size_t)m * ldc + n] = f2bf(v);
                }
            }
        }
    }
}

// ---------------- SpMM + tanh: one wave per node ----------------
__global__ __launch_bounds__(256)
void spmm_tanh(const u16* __restrict__ xl, const int* __restrict__ offs,
               const int* __restrict__ colS, const float* __restrict__ valS,
               u16* __restrict__ xout)
{
    const int wave = threadIdx.x >> 6, lane = threadIdx.x & 63;
    const int n = blockIdx.x * 4 + wave;
    if (n >= NNODES) return;
    float acc[8] = {0.f, 0.f, 0.f, 0.f, 0.f, 0.f, 0.f, 0.f};
    #pragma unroll
    for (int r = 0; r < RREL; ++r) {
        int s = offs[r * (NNODES + 1) + n];
        int e = offs[r * (NNODES + 1) + n + 1];
        const int*   cp = colS + (size_t)r * EEDGES;
        const float* vp = valS + (size_t)r * EEDGES;
        const u16*   xr = xl + (r << 9) + (lane << 3);
        for (; s < e; ++s) {
            int col = cp[s];
            float val = vp[s];
            const uint4 u = *(const uint4*)(xr + (size_t)col * XLW);
            acc[0] = fmaf(val, __uint_as_float(u.x << 16), acc[0]);
            acc[1] = fmaf(val, __uint_as_float(u.x & 0xffff0000u), acc[1]);
            acc[2] = fmaf(val, __uint_as_float(u.y << 16), acc[2]);
            acc[3] = fmaf(val, __uint_as_float(u.y & 0xffff0000u), acc[3]);
            acc[4] = fmaf(val, __uint_as_float(u.z << 16), acc[4]);
            acc[5] = fmaf(val, __uint_as_float(u.z & 0xffff0000u), acc[5]);
            acc[6] = fmaf(val, __uint_as_float(u.w << 16), acc[6]);
            acc[7] = fmaf(val, __uint_as_float(u.w & 0xffff0000u), acc[7]);
        }
    }
    uint4 o;
    o.x = (uint32_t)f2bf(tanhf(acc[0])) | ((uint32_t)f2bf(tanhf(acc[1])) << 16);
    o.y = (uint32_t)f2bf(tanhf(acc[2])) | ((uint32_t)f2bf(tanhf(acc[3])) << 16);
    o.z = (uint32_t)f2bf(tanhf(acc[4])) | ((uint32_t)f2bf(tanhf(acc[5])) << 16);
    o.w = (uint32_t)f2bf(tanhf(acc[6])) | ((uint32_t)f2bf(tanhf(acc[7])) << 16);
    *(uint4*)(xout + (size_t)n * DDIM + (lane << 3)) = o;
}

// ---------------- frame_node gather (bf16 emb -> fp32 out) ----------------
__global__ void frame_gather(const u16* __restrict__ emb, const int* __restrict__ frame_list,
                             const int* __restrict__ gold, float* __restrict__ out) {
    int t = blockIdx.x * 256 + threadIdx.x;   // 32*64
    if (t >= 32 * 64) return;
    int b = t >> 6, lane = t & 63;
    int label = frame_list[b * 16 + gold[b]];
    const u16* src = emb + (size_t)label * DDIM + (lane << 3);
    float* dst = out + (size_t)b * OUTC + FRAMES + (lane << 3);
    float4 o0 = { bf2f(src[0]), bf2f(src[1]), bf2f(src[2]), bf2f(src[3]) };
    float4 o1 = { bf2f(src[4]), bf2f(src[5]), bf2f(src[6]), bf2f(src[7]) };
    *(float4*)(dst) = o0;
    *(float4*)(dst + 4) = o1;
}

extern "C" void kernel_launch(void* const* d_in, const int* in_sizes, int n_in,
                              void* d_out, int out_size, void* d_ws, size_t ws_size,
                              hipStream_t stream) {
    const float* target_span = (const float*)d_in[0];
    const float* frame_emb   = (const float*)d_in[1];
    const float* role_emb    = (const float*)d_in[2];
    const float* rel_W0      = (const float*)d_in[3];
    const float* rel_W1      = (const float*)d_in[4];
    const float* span_W1     = (const float*)d_in[5];
    const float* span_b1     = (const float*)d_in[6];
    const float* span_W2     = (const float*)d_in[7];
    const float* span_b2     = (const float*)d_in[8];
    const float* fp_W1       = (const float*)d_in[9];
    const float* fp_b1       = (const float*)d_in[10];
    const float* fp_W2       = (const float*)d_in[11];
    const float* fp_b2       = (const float*)d_in[12];
    const float* adj_vals    = (const float*)d_in[13];
    const int* fe_ids      = (const int*)d_in[14];
    const int* adj_rows    = (const int*)d_in[15];
    const int* adj_cols    = (const int*)d_in[16];
    const int* gold_id     = (const int*)d_in[17];
    const int* frame_list  = (const int*)d_in[18];
    float* out = (float*)d_out;

    char* ws = (char*)d_ws;
    size_t off = 0;
    auto take = [&](size_t bytes) -> char* {
        char* p = ws + off;
        off = (off + bytes + 255) & ~(size_t)255;
        return p;
    };
    u16* x      = (u16*)take((size_t)MPAD * DDIM * 2);
    u16* xl     = (u16*)take((size_t)MPAD * XLW * 2);
    u16* w0t    = (u16*)take((size_t)RREL * DDIM * DDIM * 2);
    u16* w1t    = (u16*)take((size_t)RREL * DDIM * DDIM * 2);
    u16* s1t    = (u16*)take((size_t)2048 * 2048 * 2);
    u16* s2t    = (u16*)take((size_t)2048 * 512 * 2);
    u16* f1t    = (u16*)take((size_t)512 * 512 * 2);
    u16* f2t    = (u16*)take((size_t)512 * 512 * 2);
    int* counts = (int*)take((size_t)RREL * NNODES * 4);
    int* offs   = (int*)take((size_t)RREL * (NNODES + 1) * 4);
    int* cursor = (int*)take((size_t)RREL * NNODES * 4);
    int* colS   = (int*)take((size_t)RREL * EEDGES * 4);
    float* valS = (float*)take((size_t)RREL * EEDGES * 4);
    u16* tsp    = (u16*)take((size_t)128 * 2048 * 2);
    u16* h1     = (u16*)take((size_t)128 * 2048 * 2);
    u16* tn     = (u16*)take((size_t)128 * 512 * 2);
    u16* h2     = (u16*)take((size_t)128 * 512 * 2);
    u16* Qb     = (u16*)take((size_t)128 * 512 * 2);

    // CSR build (shared by both layers)
    hipMemsetAsync(counts, 0, (size_t)RREL * NNODES * 4, stream);
    hist_k<<<(RREL * EEDGES + 255) / 256, 256, 0, stream>>>(adj_rows, counts);
    scan_offsets<<<RREL, 1024, 0, stream>>>(counts, offs);
    cursor_init<<<(RREL * NNODES + 255) / 256, 256, 0, stream>>>(offs, cursor);
    scatter_k<<<(RREL * EEDGES + 255) / 256, 256, 0, stream>>>(adj_rows, adj_cols, adj_vals,
                                                               cursor, colS, valS);
    // inputs (fp32 -> bf16)
    build_x<<<(NNODES * 128 + 255) / 256, 256, 0, stream>>>(frame_emb, role_emb, fe_ids, x);
    build_tsp<<<256, 256, 0, stream>>>(target_span, tsp);

    // weight transposes (fp32 -> bf16, Bt layout for all GEMMs)
    transpose_f2b<<<dim3(16, 16, RREL), 256, 0, stream>>>(rel_W0, w0t, 512, 512);
    transpose_f2b<<<dim3(16, 16, RREL), 256, 0, stream>>>(rel_W1, w1t, 512, 512);
    transpose_f2b<<<dim3(64, 64, 1), 256, 0, stream>>>(span_W1, s1t, 2048, 2048);
    transpose_f2b<<<dim3(16, 64, 1), 256, 0, stream>>>(span_W2, s2t, 2048, 512);
    transpose_f2b<<<dim3(16, 16, 1), 256, 0, stream>>>(fp_W1, f1t, 512, 512);
    transpose_f2b<<<dim3(16, 16, 1), 256, 0, stream>>>(fp_W2, f2t, 512, 512);

    // relGCN layer 1
    gemm_bt<0, false><<<dim3(XLW / 128, MPAD / 128), 256, 0, stream>>>(
        x, w0t, xl, nullptr, 512, 512, 512, XLW, MPAD, XLW);
    spmm_tanh<<<(NNODES + 3) / 4, 256, 0, stream>>>(xl, offs, colS, valS, x);
    // relGCN layer 2
    gemm_bt<0, false><<<dim3(XLW / 128, MPAD / 128), 256, 0, stream>>>(
        x, w1t, xl, nullptr, 512, 512, 512, XLW, MPAD, XLW);
    spmm_tanh<<<(NNODES + 3) / 4, 256, 0, stream>>>(xl, offs, colS, valS, x);

    // span MLP chain (M padded to 128)
    gemm_bt<1, false><<<dim3(16, 1), 256, 0, stream>>>(tsp, s1t, h1, span_b1,
                                                       2048, 2048, 2048, 2048, 128, 2048);
    gemm_bt<2, false><<<dim3(4, 1), 256, 0, stream>>>(h1, s2t, tn, span_b2,
                                                      2048, 2048, 2048, 512, 128, 512);
    gemm_bt<1, false><<<dim3(4, 1), 256, 0, stream>>>(tn, f1t, h2, fp_b1,
                                                      512, 512, 512, 512, 128, 512);
    gemm_bt<3, false><<<dim3(4, 1), 256, 0, stream>>>(h2, f2t, Qb, fp_b2,
                                                      512, 512, 512, 512, 128, 512);

    // pred_frame_weight = Q @ emb^T  (emb already [n][k]); writes out[:, :1200] as fp32
    gemm_bt<0, true><<<dim3((FRAMES + 127) / 128, 1), 256, 0, stream>>>(
        Qb, x, out, nullptr, 512, 512, 512, OUTC, 32, FRAMES);
    // frame_node gather; writes out[:, 1200:1712] as fp32
    frame_gather<<<8, 256, 0, stream>>>(x, frame_list, gold_id, out);
}

// Round 3
// 546.197 us; speedup vs baseline: 1.1866x; 1.1866x over previous
//
#include <hip/hip_runtime.h>
#include <hip/hip_bf16.h>
#include <stdint.h>

typedef unsigned short u16;
typedef __attribute__((ext_vector_type(8))) short short8;
typedef __attribute__((ext_vector_type(4))) float float4v;

#define NNODES 11201
#define MPAD   11264
#define EEDGES 100000
#define RREL   5
#define DDIM   512
#define XLW    2560      // RREL*DDIM
#define FRAMES 1200
#define OUTC   1712      // FRAMES + DDIM

__device__ __forceinline__ float bf2f(u16 h) {
    return __uint_as_float(((uint32_t)h) << 16);
}
__device__ __forceinline__ u16 f2bf(float f) {
    uint32_t x = __float_as_uint(f);
    x += 0x7fffu + ((x >> 16) & 1u);   // RNE
    return (u16)(x >> 16);
}
__device__ __forceinline__ float fast_tanh(float v) {
    v = fminf(fmaxf(v, -10.f), 10.f);
    float ex = __expf(2.f * v);
    return (ex - 1.f) / (ex + 1.f);
}

// ---------------- CSR build ----------------
__global__ void hist_k(const int* __restrict__ rows, int* __restrict__ counts) {
    int tid = blockIdx.x * 256 + threadIdx.x;
    if (tid >= RREL * EEDGES) return;
    int r = tid / EEDGES;
    atomicAdd(&counts[r * NNODES + rows[tid]], 1);
}

__global__ __launch_bounds__(1024) void scan_offsets(const int* __restrict__ counts,
                                                     int* __restrict__ offs) {
    int r = blockIdx.x;
    const int* c = counts + (size_t)r * NNODES;
    int* o = offs + (size_t)r * (NNODES + 1);
    __shared__ int wsum[16];
    __shared__ int carry_s;
    const int lane = threadIdx.x & 63, wid = threadIdx.x >> 6;
    if (threadIdx.x == 0) carry_s = 0;
    __syncthreads();
    for (int base = 0; base < NNODES; base += 1024) {
        int idx = base + threadIdx.x;
        int orig = (idx < NNODES) ? c[idx] : 0;
        int v = orig;
        #pragma unroll
        for (int d = 1; d < 64; d <<= 1) {
            int t = __shfl_up(v, d, 64);
            if (lane >= d) v += t;
        }
        if (lane == 63) wsum[wid] = v;
        __syncthreads();
        if (wid == 0) {
            int wv = (lane < 16) ? wsum[lane] : 0;
            #pragma unroll
            for (int d = 1; d < 16; d <<= 1) {
                int t = __shfl_up(wv, d, 64);
                if (lane >= d) wv += t;
            }
            if (lane < 16) wsum[lane] = wv;
        }
        __syncthreads();
        int incl = carry_s + ((wid > 0) ? wsum[wid - 1] : 0) + v;
        if (idx < NNODES) o[idx] = incl - orig;   // exclusive
        __syncthreads();
        if (threadIdx.x == 1023) carry_s = incl;
    }
    __syncthreads();
    if (threadIdx.x == 0) o[NNODES] = carry_s;
}

__global__ void cursor_init(const int* __restrict__ offs, int* __restrict__ cursor) {
    int i = blockIdx.x * 256 + threadIdx.x;
    if (i >= RREL * NNODES) return;
    int r = i / NNODES, n = i - r * NNODES;
    cursor[i] = offs[r * (NNODES + 1) + n];
}

__global__ void scatter_k(const int* __restrict__ rows, const int* __restrict__ cols,
                          const float* __restrict__ vals, int* __restrict__ cursor,
                          int* __restrict__ colS, float* __restrict__ valS) {
    int tid = blockIdx.x * 256 + threadIdx.x;
    if (tid >= RREL * EEDGES) return;
    int r = tid / EEDGES;
    int row = rows[tid];
    int pos = atomicAdd(&cursor[r * NNODES + row], 1);
    colS[(size_t)r * EEDGES + pos] = cols[tid];
    valS[(size_t)r * EEDGES + pos] = vals[tid];
}

// ---------------- input assembly (fp32 -> bf16) ----------------
__global__ void build_x(const float* __restrict__ frame_emb, const float* __restrict__ role_emb,
                        const int* __restrict__ fe_ids, u16* __restrict__ x) {
    int t = blockIdx.x * 256 + threadIdx.x;
    int row = t >> 7, c4 = (t & 127) << 2;
    if (row >= NNODES) return;
    const float* src = (row < FRAMES) ? (frame_emb + (size_t)row * DDIM)
                                      : (role_emb + (size_t)fe_ids[row - FRAMES] * DDIM);
    float4 v = *(const float4*)(src + c4);
    ushort4 o = { f2bf(v.x), f2bf(v.y), f2bf(v.z), f2bf(v.w) };
    *(ushort4*)(x + (size_t)row * DDIM + c4) = o;
}

__global__ void build_tsp(const float* __restrict__ ts, u16* __restrict__ tsp) {
    int t = blockIdx.x * 256 + threadIdx.x;       // 65536 threads
    int row = t >> 9, c4 = (t & 511) << 2;
    ushort4 o = {0, 0, 0, 0};
    if (row < 32) {
        float4 v = *(const float4*)(ts + (size_t)row * 2048 + c4);
        o = ushort4{ f2bf(v.x), f2bf(v.y), f2bf(v.z), f2bf(v.w) };
    }
    *(ushort4*)(tsp + (size_t)row * 2048 + c4) = o;
}

// ---------------- fp32 -> bf16 transpose, z-batched with ldOut + z-col-offset ---------
// out[(c) * ldOut + z*rows + r] = in_z[r][c]
__global__ void transpose_f2b(const float* __restrict__ in, u16* __restrict__ out,
                              int rows, int cols, int ldOut) {
    __shared__ u16 tile[32][33];
    in += (size_t)blockIdx.z * rows * cols;
    const size_t zoff = (size_t)blockIdx.z * rows;
    int c0 = blockIdx.x * 32, r0 = blockIdx.y * 32;
    int tx = threadIdx.x & 31, ty = threadIdx.x >> 5;   // 256 threads
    #pragma unroll
    for (int i = 0; i < 4; ++i) {
        int rr = ty + i * 8;
        tile[rr][tx] = f2bf(in[(size_t)(r0 + rr) * cols + c0 + tx]);
    }
    __syncthreads();
    #pragma unroll
    for (int i = 0; i < 4; ++i) {
        int rr = ty + i * 8;
        out[(size_t)(c0 + rr) * ldOut + zoff + r0 + tx] = tile[tx][rr];
    }
}

// ---------------- BT-GEMM: C[m][n] = sum_k A[m][k]*Bt[n][k], m97 structure ----------------
// EPI: 0=store, 1=bias+relu, 2=bias, 3=bias+tanh, 4=tanh (no bias). FOUT: fp32 store.
template<int EPI, bool FOUT>
__global__ __launch_bounds__(256)
void gemm_bt(const u16* __restrict__ A, const u16* __restrict__ Bt,
             void* __restrict__ Cv, const float* __restrict__ bias,
             int K, int lda, int ldb, int ldc, int mGuard, int nGuard)
{
    __shared__ u16 As[128 * 32];
    __shared__ u16 Bs[128 * 32];
    const int tid = threadIdx.x;
    const int wave = tid >> 6, lane = tid & 63;
    const int m0 = blockIdx.y * 128, n0 = blockIdx.x * 128;
    const int srow = lane >> 2;
    const int skoff = (lane & 3) << 3;
    const int fr = lane & 15, quad = lane >> 4;
    const int wm = (wave & 1) << 6, wn = (wave >> 1) << 6;
    float4v acc[4][4] = {};

    for (int k0 = 0; k0 < K; k0 += 32) {
        #pragma unroll
        for (int i = 0; i < 2; ++i) {
            const int rb = (wave + i * 4) << 4;
            const u16* ga = A  + (size_t)(m0 + rb + srow) * lda + (k0 + skoff);
            const u16* gb = Bt + (size_t)(n0 + rb + srow) * ldb + (k0 + skoff);
            __builtin_amdgcn_global_load_lds(
                (const __attribute__((address_space(1))) unsigned int*)ga,
                (__attribute__((address_space(3))) unsigned int*)(As + rb * 32), 16, 0, 0);
            __builtin_amdgcn_global_load_lds(
                (const __attribute__((address_space(1))) unsigned int*)gb,
                (__attribute__((address_space(3))) unsigned int*)(Bs + rb * 32), 16, 0, 0);
        }
        __syncthreads();
        short8 a[4], b[4];
        #pragma unroll
        for (int t = 0; t < 4; ++t)
            a[t] = *(const short8*)(As + ((wm + t * 16 + fr) << 5) + (quad << 3));
        #pragma unroll
        for (int t = 0; t < 4; ++t)
            b[t] = *(const short8*)(Bs + ((wn + t * 16 + fr) << 5) + (quad << 3));
        #pragma unroll
        for (int i = 0; i < 4; ++i)
            #pragma unroll
            for (int j = 0; j < 4; ++j)
                acc[i][j] = __builtin_amdgcn_mfma_f32_16x16x32_bf16(a[i], b[j], acc[i][j], 0, 0, 0);
        __syncthreads();
    }

    #pragma unroll
    for (int i = 0; i < 4; ++i) {
        #pragma unroll
        for (int j = 0; j < 4; ++j) {
            const int n = n0 + wn + j * 16 + fr;
            float bv = 0.f;
            if (EPI == 1 || EPI == 2 || EPI == 3) { if (n < nGuard) bv = bias[n]; }
            #pragma unroll
            for (int rg = 0; rg < 4; ++rg) {
                const int m = m0 + wm + i * 16 + (quad << 2) + rg;
                if (m < mGuard && n < nGuard) {
                    float v = acc[i][j][rg];
                    if (EPI == 1 || EPI == 2 || EPI == 3) v += bv;
                    if (EPI == 1) v = fmaxf(v, 0.f);
                    if (EPI == 3 || EPI == 4) v = fast_tanh(v);
                    if (FOUT) ((float*)Cv)[(size_t)m * ldc + n] = v;
                    else      ((u16*)Cv)[(size_t)m * ldc + n] = f2bf(v);
                }
            }
        }
    }
}

// ---------------- split-K BT-GEMM: atomic fp32 accumulate (exact 128-multiples) --------
__global__ __launch_bounds__(256)
void gemm_bt_sk(const u16* __restrict__ A, const u16* __restrict__ Bt,
                float* __restrict__ Cf, int K, int Kc, int lda, int ldb, int ldc)
{
    __shared__ u16 As[128 * 32];
    __shared__ u16 Bs[128 * 32];
    const int tid = threadIdx.x;
    const int wave = tid >> 6, lane = tid & 63;
    const int m0 = blockIdx.y * 128, n0 = blockIdx.x * 128;
    const int kb = blockIdx.z * Kc;
    const int ke = (kb + Kc < K) ? (kb + Kc) : K;
    const int srow = lane >> 2;
    const int skoff = (lane & 3) << 3;
    const int fr = lane & 15, quad = lane >> 4;
    const int wm = (wave & 1) << 6, wn = (wave >> 1) << 6;
    float4v acc[4][4] = {};

    for (int k0 = kb; k0 < ke; k0 += 32) {
        #pragma unroll
        for (int i = 0; i < 2; ++i) {
            const int rb = (wave + i * 4) << 4;
            const u16* ga = A  + (size_t)(m0 + rb + srow) * lda + (k0 + skoff);
            const u16* gb = Bt + (size_t)(n0 + rb + srow) * ldb + (k0 + skoff);
            __builtin_amdgcn_global_load_lds(
                (const __attribute__((address_space(1))) unsigned int*)ga,
                (__attribute__((address_space(3))) unsigned int*)(As + rb * 32), 16, 0, 0);
            __builtin_amdgcn_global_load_lds(
                (const __attribute__((address_space(1))) unsigned int*)gb,
                (__attribute__((address_space(3))) unsigned int*)(Bs + rb * 32), 16, 0, 0);
        }
        __syncthreads();
        short8 a[4], b[4];
        #pragma unroll
        for (int t = 0; t < 4; ++t)
            a[t] = *(const short8*)(As + ((wm + t * 16 + fr) << 5) + (quad << 3));
        #pragma unroll
        for (int t = 0; t < 4; ++t)
            b[t] = *(const short8*)(Bs + ((wn + t * 16 + fr) << 5) + (quad << 3));
        #pragma unroll
        for (int i = 0; i < 4; ++i)
            #pragma unroll
            for (int j = 0; j < 4; ++j)
                acc[i][j] = __builtin_amdgcn_mfma_f32_16x16x32_bf16(a[i], b[j], acc[i][j], 0, 0, 0);
        __syncthreads();
    }

    #pragma unroll
    for (int i = 0; i < 4; ++i)
        #pragma unroll
        for (int j = 0; j < 4; ++j) {
            const int n = n0 + wn + j * 16 + fr;
            #pragma unroll
            for (int rg = 0; rg < 4; ++rg) {
                const int m = m0 + wm + i * 16 + (quad << 2) + rg;
                atomicAdd(&Cf[(size_t)m * ldc + n], acc[i][j][rg]);
            }
        }
}

// split-K epilogue: bias + act + bf16 store. ACT: 1=relu, 2=none, 3=tanh
template<int ACT>
__global__ void sk_ep(const float* __restrict__ Cf, const float* __restrict__ bias,
                      u16* __restrict__ outp, int Ncols) {
    int t = blockIdx.x * 256 + threadIdx.x;
    if (t >= 128 * Ncols / 4) return;
    int i = t << 2;
    int col = i & (Ncols - 1);
    float4 v = *(const float4*)(Cf + i);
    v.x += bias[col]; v.y += bias[col + 1]; v.z += bias[col + 2]; v.w += bias[col + 3];
    if (ACT == 1) { v.x = fmaxf(v.x, 0.f); v.y = fmaxf(v.y, 0.f);
                    v.z = fmaxf(v.z, 0.f); v.w = fmaxf(v.w, 0.f); }
    if (ACT == 3) { v.x = fast_tanh(v.x); v.y = fast_tanh(v.y);
                    v.z = fast_tanh(v.z); v.w = fast_tanh(v.w); }
    ushort4 o = { f2bf(v.x), f2bf(v.y), f2bf(v.z), f2bf(v.w) };
    *(ushort4*)(outp + i) = o;
}

// ---------------- gather-aggregate: agg[n][r*512+d] = sum_e vals[r][e] * x[col][d] ------
__device__ __forceinline__ void fma8(float* acc, uint4 u, float val) {
    acc[0] = fmaf(val, __uint_as_float(u.x << 16), acc[0]);
    acc[1] = fmaf(val, __uint_as_float(u.x & 0xffff0000u), acc[1]);
    acc[2] = fmaf(val, __uint_as_float(u.y << 16), acc[2]);
    acc[3] = fmaf(val, __uint_as_float(u.y & 0xffff0000u), acc[3]);
    acc[4] = fmaf(val, __uint_as_float(u.z << 16), acc[4]);
    acc[5] = fmaf(val, __uint_as_float(u.z & 0xffff0000u), acc[5]);
    acc[6] = fmaf(val, __uint_as_float(u.w << 16), acc[6]);
    acc[7] = fmaf(val, __uint_as_float(u.w & 0xffff0000u), acc[7]);
}

__global__ __launch_bounds__(256)
void spmm_agg(const u16* __restrict__ x, const int* __restrict__ offs,
              const int* __restrict__ colS, const float* __restrict__ valS,
              u16* __restrict__ agg)
{
    const int wave = threadIdx.x >> 6, lane = threadIdx.x & 63;
    const int n = blockIdx.x * 4 + wave;
    if (n >= NNODES) return;
    const u16* xr = x + (lane << 3);
    #pragma unroll
    for (int r = 0; r < RREL; ++r) {
        int s = offs[r * (NNODES + 1) + n];
        const int e = offs[r * (NNODES + 1) + n + 1];
        const int*   cp = colS + (size_t)r * EEDGES;
        const float* vp = valS + (size_t)r * EEDGES;
        float acc[8] = {0.f, 0.f, 0.f, 0.f, 0.f, 0.f, 0.f, 0.f};
        for (; s + 4 <= e; s += 4) {       // 4 gathers in flight
            int   c0 = cp[s], c1 = cp[s + 1], c2 = cp[s + 2], c3 = cp[s + 3];
            float v0 = vp[s], v1 = vp[s + 1], v2 = vp[s + 2], v3 = vp[s + 3];
            uint4 u0 = *(const uint4*)(xr + (size_t)c0 * DDIM);
            uint4 u1 = *(const uint4*)(xr + (size_t)c1 * DDIM);
            uint4 u2 = *(const uint4*)(xr + (size_t)c2 * DDIM);
            uint4 u3 = *(const uint4*)(xr + (size_t)c3 * DDIM);
            fma8(acc, u0, v0); fma8(acc, u1, v1); fma8(acc, u2, v2); fma8(acc, u3, v3);
        }
        for (; s < e; ++s) {
            int col = cp[s];
            float val = vp[s];
            uint4 u = *(const uint4*)(xr + (size_t)col * DDIM);
            fma8(acc, u, val);
        }
        uint4 o;
        o.x = (uint32_t)f2bf(acc[0]) | ((uint32_t)f2bf(acc[1]) << 16);
        o.y = (uint32_t)f2bf(acc[2]) | ((uint32_t)f2bf(acc[3]) << 16);
        o.z = (uint32_t)f2bf(acc[4]) | ((uint32_t)f2bf(acc[5]) << 16);
        o.w = (uint32_t)f2bf(acc[6]) | ((uint32_t)f2bf(acc[7]) << 16);
        *(uint4*)(agg + (size_t)n * XLW + (r << 9) + (lane << 3)) = o;
    }
}

// ---------------- frame_node gather (bf16 emb -> fp32 out) ----------------
__global__ void frame_gather(const u16* __restrict__ emb, const int* __restrict__ frame_list,
                             const int* __restrict__ gold, float* __restrict__ out) {
    int t = blockIdx.x * 256 + threadIdx.x;   // 32*64
    if (t >= 32 * 64) return;
    int b = t >> 6, lane = t & 63;
    int label = frame_list[b * 16 + gold[b]];
    const u16* src = emb + (size_t)label * DDIM + (lane << 3);
    float* dst = out + (size_t)b * OUTC + FRAMES + (lane << 3);
    float4 o0 = { bf2f(src[0]), bf2f(src[1]), bf2f(src[2]), bf2f(src[3]) };
    float4 o1 = { bf2f(src[4]), bf2f(src[5]), bf2f(src[6]), bf2f(src[7]) };
    *(float4*)(dst) = o0;
    *(float4*)(dst + 4) = o1;
}

extern "C" void kernel_launch(void* const* d_in, const int* in_sizes, int n_in,
                              void* d_out, int out_size, void* d_ws, size_t ws_size,
                              hipStream_t stream) {
    const float* target_span = (const float*)d_in[0];
    const float* frame_emb   = (const float*)d_in[1];
    const float* role_emb    = (const float*)d_in[2];
    const float* rel_W0      = (const float*)d_in[3];
    const float* rel_W1      = (const float*)d_in[4];
    const float* span_W1     = (const float*)d_in[5];
    const float* span_b1     = (const float*)d_in[6];
    const float* span_W2     = (const float*)d_in[7];
    const float* span_b2     = (const float*)d_in[8];
    const float* fp_W1       = (const float*)d_in[9];
    const float* fp_b1       = (const float*)d_in[10];
    const float* fp_W2       = (const float*)d_in[11];
    const float* fp_b2       = (const float*)d_in[12];
    const float* adj_vals    = (const float*)d_in[13];
    const int* fe_ids      = (const int*)d_in[14];
    const int* adj_rows    = (const int*)d_in[15];
    const int* adj_cols    = (const int*)d_in[16];
    const int* gold_id     = (const int*)d_in[17];
    const int* frame_list  = (const int*)d_in[18];
    float* out = (float*)d_out;

    char* ws = (char*)d_ws;
    size_t off = 0;
    auto take = [&](size_t bytes) -> char* {
        char* p = ws + off;
        off = (off + bytes + 255) & ~(size_t)255;
        return p;
    };
    u16* x      = (u16*)take((size_t)MPAD * DDIM * 2);
    u16* agg    = (u16*)take((size_t)MPAD * XLW * 2);
    u16* w0t    = (u16*)take((size_t)512 * XLW * 2);     // Wcat0^T: [512 n][2560 k]
    u16* w1t    = (u16*)take((size_t)512 * XLW * 2);
    u16* s1t    = (u16*)take((size_t)2048 * 2048 * 2);
    u16* s2t    = (u16*)take((size_t)512 * 2048 * 2);
    u16* f1t    = (u16*)take((size_t)512 * 512 * 2);
    u16* f2t    = (u16*)take((size_t)512 * 512 * 2);
    int* counts = (int*)take((size_t)RREL * NNODES * 4);
    int* offs   = (int*)take((size_t)RREL * (NNODES + 1) * 4);
    int* cursor = (int*)take((size_t)RREL * NNODES * 4);
    int* colS   = (int*)take((size_t)RREL * EEDGES * 4);
    float* valS = (float*)take((size_t)RREL * EEDGES * 4);
    u16* tsp    = (u16*)take((size_t)128 * 2048 * 2);
    u16* h1     = (u16*)take((size_t)128 * 2048 * 2);
    u16* tn     = (u16*)take((size_t)128 * 512 * 2);
    u16* h2     = (u16*)take((size_t)128 * 512 * 2);
    u16* Qb     = (u16*)take((size_t)128 * 512 * 2);
    float* CfAll = (float*)take((size_t)(128 * 2048 + 3 * 128 * 512) * 4);
    float* Cf1 = CfAll;
    float* Cf2 = Cf1 + 128 * 2048;
    float* Cf3 = Cf2 + 128 * 512;
    float* Cf4 = Cf3 + 128 * 512;

    hipMemsetAsync(counts, 0, (size_t)RREL * NNODES * 4, stream);
    hipMemsetAsync(CfAll, 0, (size_t)(128 * 2048 + 3 * 128 * 512) * 4, stream);

    // CSR build (shared by both layers)
    hist_k<<<(RREL * EEDGES + 255) / 256, 256, 0, stream>>>(adj_rows, counts);
    scan_offsets<<<RREL, 1024, 0, stream>>>(counts, offs);
    cursor_init<<<(RREL * NNODES + 255) / 256, 256, 0, stream>>>(offs, cursor);
    scatter_k<<<(RREL * EEDGES + 255) / 256, 256, 0, stream>>>(adj_rows, adj_cols, adj_vals,
                                                               cursor, colS, valS);
    // inputs (fp32 -> bf16)
    build_x<<<(NNODES * 128 + 255) / 256, 256, 0, stream>>>(frame_emb, role_emb, fe_ids, x);
    build_tsp<<<256, 256, 0, stream>>>(target_span, tsp);

    // weight transposes. Wcat layout: wXt[n][r*512+i] = W_r[i][n]
    transpose_f2b<<<dim3(16, 16, RREL), 256, 0, stream>>>(rel_W0, w0t, 512, 512, XLW);
    transpose_f2b<<<dim3(16, 16, RREL), 256, 0, stream>>>(rel_W1, w1t, 512, 512, XLW);
    transpose_f2b<<<dim3(64, 64, 1), 256, 0, stream>>>(span_W1, s1t, 2048, 2048, 2048);
    transpose_f2b<<<dim3(16, 64, 1), 256, 0, stream>>>(span_W2, s2t, 2048, 512, 2048);
    transpose_f2b<<<dim3(16, 16, 1), 256, 0, stream>>>(fp_W1, f1t, 512, 512, 512);
    transpose_f2b<<<dim3(16, 16, 1), 256, 0, stream>>>(fp_W2, f2t, 512, 512, 512);

    // relGCN layer 1: gather-aggregate then single K=2560 GEMM with fused tanh (in-place x)
    spmm_agg<<<(NNODES + 3) / 4, 256, 0, stream>>>(x, offs, colS, valS, agg);
    gemm_bt<4, false><<<dim3(4, MPAD / 128), 256, 0, stream>>>(
        agg, w0t, x, nullptr, XLW, XLW, XLW, 512, NNODES, 512);
    // relGCN layer 2
    spmm_agg<<<(NNODES + 3) / 4, 256, 0, stream>>>(x, offs, colS, valS, agg);
    gemm_bt<4, false><<<dim3(4, MPAD / 128), 256, 0, stream>>>(
        agg, w1t, x, nullptr, XLW, XLW, XLW, 512, NNODES, 512);

    // span MLP chain via split-K + epilogues
    gemm_bt_sk<<<dim3(16, 1, 8), 256, 0, stream>>>(tsp, s1t, Cf1, 2048, 256, 2048, 2048, 2048);
    sk_ep<1><<<(128 * 2048 / 4 + 255) / 256, 256, 0, stream>>>(Cf1, span_b1, h1, 2048);
    gemm_bt_sk<<<dim3(4, 1, 8), 256, 0, stream>>>(h1, s2t, Cf2, 2048, 256, 2048, 2048, 512);
    sk_ep<2><<<(128 * 512 / 4 + 255) / 256, 256, 0, stream>>>(Cf2, span_b2, tn, 512);
    gemm_bt_sk<<<dim3(4, 1, 4), 256, 0, stream>>>(tn, f1t, Cf3, 512, 128, 512, 512, 512);
    sk_ep<1><<<(128 * 512 / 4 + 255) / 256, 256, 0, stream>>>(Cf3, fp_b1, h2, 512);
    gemm_bt_sk<<<dim3(4, 1, 4), 256, 0, stream>>>(h2, f2t, Cf4, 512, 128, 512, 512, 512);
    sk_ep<3><<<(128 * 512 / 4 + 255) / 256, 256, 0, stream>>>(Cf4, fp_b2, Qb, 512);

    // pred_frame_weight = Q @ emb^T ; writes out[:, :1200] as fp32
    gemm_bt<0, true><<<dim3((FRAMES + 127) / 128, 1), 256, 0, stream>>>(
        Qb, x, out, nullptr, 512, 512, 512, OUTC, 32, FRAMES);
    // frame_node gather; writes out[:, 1200:1712] as fp32
    frame_gather<<<8, 256, 0, stream>>>(x, frame_list, gold_id, out);
}